// Round 1
// baseline (871.596 us; speedup 1.0000x reference)
//
#include <hip/hip_runtime.h>
#include <hip/hip_bf16.h>

#define NK 1024        // codebook size
#define ND 64          // embedding dim
#define NV 131072      // 32*64*64 input vectors
#define DECAY_F 0.99f
#define OMD_F 0.01f    // fl32(1.0 - 0.99) == fl32(0.01)
#define EPS_F 1e-5f
#define KEPS_F 0.01024f // fl32(1024 * 1e-5)

// ---- ws layout (bytes) ----
// 0    : csq[1024]   f32
// 4096 : ucraw[1024] f32
// 8192 : n_acc f32
// 8196 : usage f32
// 8200 : loss  f64
// 8224 : indices[NV] i32  (512 KB)

// ---------------------------------------------------------------------------
// Kernel 1: codebook_sq with numpy pairwise-8 rounding; zero accumulators.
// ---------------------------------------------------------------------------
__global__ __launch_bounds__(256) void vq_prep(const float* __restrict__ emb,
                                               float* __restrict__ csq,
                                               float* n_acc, float* usage,
                                               double* loss)
{
    int k = blockIdx.x * 256 + threadIdx.x;
    if (k == 0) { *n_acc = 0.f; *usage = 0.f; *loss = 0.0; }
    float p[ND];
    const float4* e4 = reinterpret_cast<const float4*>(emb + (size_t)k * ND);
#pragma unroll
    for (int i = 0; i < 16; ++i) {
        float4 v = e4[i];
        p[4*i+0] = __fmul_rn(v.x, v.x);
        p[4*i+1] = __fmul_rn(v.y, v.y);
        p[4*i+2] = __fmul_rn(v.z, v.z);
        p[4*i+3] = __fmul_rn(v.w, v.w);
    }
    float r[8];
#pragma unroll
    for (int j = 0; j < 8; ++j) r[j] = p[j];
#pragma unroll
    for (int i = 8; i < ND; i += 8)
#pragma unroll
        for (int j = 0; j < 8; ++j) r[j] = __fadd_rn(r[j], p[i+j]);
    csq[k] = __fadd_rn(__fadd_rn(__fadd_rn(r[0], r[1]), __fadd_rn(r[2], r[3])),
                       __fadd_rn(__fadd_rn(r[4], r[5]), __fadd_rn(r[6], r[7])));
}

// ---------------------------------------------------------------------------
// Kernel 2: per-thread argmin over 1024 codes (LDS-tiled embeddings, broadcast
// reads), interleaved encodings zero-fill, then 1.0 scatter + quantized_flow
// + loss partial. 512 threads/block, 256 blocks (1 thread = 1 input vector).
// ---------------------------------------------------------------------------
#define TILE 128
#define NTILES 8

__global__ __launch_bounds__(512, 2) void vq_assign(
    const float* __restrict__ x_in, const float* __restrict__ emb,
    const float* __restrict__ csq, float* __restrict__ out_qf,
    float* __restrict__ out_enc, int* __restrict__ indices,
    double* __restrict__ loss_acc)
{
    __shared__ float4 lds_e4[TILE * 16];   // 32 KB tile
    __shared__ float  lds_csq[TILE];
    __shared__ double lds_ls[8];
    float* lds_e = (float*)lds_e4;

    const int tid  = threadIdx.x;
    const int lane = tid & 63;
    const int wv   = tid >> 6;
    const int n    = blockIdx.x * 512 + tid;
    const int wrowbase = blockIdx.x * 512 + wv * 64;  // rows owned by this wave

    // load own input vector into registers
    float x[ND];
    const float4* xv4 = reinterpret_cast<const float4*>(x_in + (size_t)n * ND);
#pragma unroll
    for (int i = 0; i < 16; ++i) {
        float4 v = xv4[i];
        x[4*i+0] = v.x; x[4*i+1] = v.y; x[4*i+2] = v.z; x[4*i+3] = v.w;
    }

    // input_sq with numpy pairwise-8 rounding (no FP contraction)
    float isq;
    {
        float r[8];
#pragma unroll
        for (int j = 0; j < 8; ++j) r[j] = __fmul_rn(x[j], x[j]);
#pragma unroll
        for (int i = 8; i < ND; i += 8)
#pragma unroll
            for (int j = 0; j < 8; ++j)
                r[j] = __fadd_rn(r[j], __fmul_rn(x[i+j], x[i+j]));
        isq = __fadd_rn(__fadd_rn(__fadd_rn(r[0], r[1]), __fadd_rn(r[2], r[3])),
                        __fadd_rn(__fadd_rn(r[4], r[5]), __fadd_rn(r[6], r[7])));
    }

    float best = 3.4e38f;
    int bestk = 0;

    for (int t = 0; t < NTILES; ++t) {
        // stage 128 codes into LDS (coalesced float4)
        {
            const float4* src = reinterpret_cast<const float4*>(emb + (size_t)t * TILE * ND);
            float4* dst = lds_e4;
#pragma unroll
            for (int j = 0; j < 4; ++j) dst[tid + j * 512] = src[tid + j * 512];
            if (tid < TILE) lds_csq[tid] = csq[t * TILE + tid];
        }
        __syncthreads();

        for (int kc = 0; kc < 4; ++kc) {
#pragma unroll 2
            for (int kk = 0; kk < 32; ++kk) {
                int k = kc * 32 + kk;
                const float4* e4 = reinterpret_cast<const float4*>(lds_e + k * ND);
                float dot = 0.f;
#pragma unroll
                for (int d4 = 0; d4 < 16; ++d4) {
                    float4 ev = e4[d4];
                    dot = __builtin_fmaf(x[4*d4+0], ev.x, dot);
                    dot = __builtin_fmaf(x[4*d4+1], ev.y, dot);
                    dot = __builtin_fmaf(x[4*d4+2], ev.z, dot);
                    dot = __builtin_fmaf(x[4*d4+3], ev.w, dot);
                }
                float dist = __fsub_rn(__fadd_rn(isq, lds_csq[k]), __fmul_rn(2.0f, dot));
                if (dist < best) { best = dist; bestk = t * TILE + k; }  // first-index ties
            }
            // interleaved encodings zero-fill: 2 rows/wave/chunk, coalesced 1KB stores
            {
                int rb = (t * 4 + kc) * 2;
#pragma unroll
                for (int rr = 0; rr < 2; ++rr) {
                    int row = wrowbase + rb + rr;
                    float4* dst = reinterpret_cast<float4*>(out_enc + (size_t)row * NK);
                    float4 z = make_float4(0.f, 0.f, 0.f, 0.f);
#pragma unroll
                    for (int j = 0; j < 4; ++j) dst[j * 64 + lane] = z;
                }
            }
        }
        __syncthreads();
    }

    indices[n] = bestk;

    // ensure all our zero-stores are complete before placing the 1.0
    asm volatile("s_waitcnt vmcnt(0)" ::: "memory");
    out_enc[(size_t)n * NK + bestk] = 1.0f;

    // cooperative quantized_flow + loss: wave handles its 64 rows, lane = dim
    float lsum = 0.f;
    for (int r = 0; r < 64; ++r) {
        int kr  = __shfl(bestk, r, 64);
        int row = wrowbase + r;
        float xv = x_in[(size_t)row * ND + lane];
        float ev = emb[(size_t)kr * ND + lane];
        out_qf[(size_t)row * ND + lane] = __fadd_rn(xv, __fsub_rn(ev, xv));
        float dd = __fsub_rn(xv, ev);
        lsum = __builtin_fmaf(dd, dd, lsum);
    }
    double ls = (double)lsum;
#pragma unroll
    for (int off = 32; off >= 1; off >>= 1) ls += __shfl_xor(ls, off, 64);
    if (lane == 0) lds_ls[wv] = ls;
    __syncthreads();
    if (tid == 0) {
        double s = 0.0;
        for (int w = 0; w < 8; ++w) s += lds_ls[w];
        atomicAdd(loss_acc, s);
    }
}

// ---------------------------------------------------------------------------
// Kernel 3: segment sums — one block per code, scan index array via ballot.
// ---------------------------------------------------------------------------
__global__ __launch_bounds__(256) void vq_segsum(
    const float* __restrict__ x_in, const int* __restrict__ indices,
    const float* __restrict__ ema_w, const float* __restrict__ ema_cs,
    float* __restrict__ out_updw, float* __restrict__ ucraw,
    float* __restrict__ n_acc, float* __restrict__ usage)
{
    __shared__ float sacc[4][64];
    __shared__ int   scnt[4];
    const int k    = blockIdx.x;
    const int tid  = threadIdx.x;
    const int lane = tid & 63;
    const int wv   = tid >> 6;

    float acc = 0.f;
    int cnt = 0;
    const int base = wv * (NV / 4);
    for (int i = 0; i < (NV / 4) / 64; ++i) {
        int n0  = base + i * 64;
        int idx = indices[n0 + lane];
        unsigned long long m = __ballot(idx == k);
        cnt += __popcll(m);
        while (m) {
            int r = __ffsll((long long)m) - 1;
            m &= m - 1;
            acc = __fadd_rn(acc, x_in[(size_t)(n0 + r) * ND + lane]);
        }
    }
    sacc[wv][lane] = acc;
    if (lane == 0) scnt[wv] = cnt;
    __syncthreads();
    if (tid < 64) {
        float s = __fadd_rn(__fadd_rn(__fadd_rn(sacc[0][tid], sacc[1][tid]), sacc[2][tid]), sacc[3][tid]);
        out_updw[(size_t)k * ND + tid] =
            __fadd_rn(__fmul_rn(ema_w[(size_t)k * ND + tid], DECAY_F), __fmul_rn(OMD_F, s));
    }
    if (tid == 0) {
        int c = scnt[0] + scnt[1] + scnt[2] + scnt[3];
        float uc = __fadd_rn(__fmul_rn(ema_cs[k], DECAY_F), __fmul_rn(OMD_F, (float)c));
        ucraw[k] = uc;
        atomicAdd(n_acc, uc);
        if (c > 0) atomicAdd(usage, 1.0f);
    }
}

// ---------------------------------------------------------------------------
// Kernel 4: finalize — normalize cluster sizes, upd_embeddings, scalars.
// ---------------------------------------------------------------------------
__global__ __launch_bounds__(256) void vq_final(
    const float* __restrict__ ucraw, const float* __restrict__ n_acc,
    const float* __restrict__ usage, const double* __restrict__ loss_acc,
    const float* __restrict__ out_updw, float* __restrict__ out_upde,
    float* __restrict__ out_uc, float* __restrict__ out_usage,
    float* __restrict__ out_loss)
{
    int gid = blockIdx.x * 256 + threadIdx.x;
    int k = gid >> 6, d = gid & 63;
    float n_tot = *n_acc;
    float ucf = __fmul_rn(__fdiv_rn(__fadd_rn(ucraw[k], EPS_F), __fadd_rn(n_tot, KEPS_F)), n_tot);
    out_upde[gid] = __fdiv_rn(out_updw[gid], __fadd_rn(ucf, EPS_F));
    if (d == 0) out_uc[k] = ucf;
    if (gid == 0) {
        *out_usage = __fdiv_rn(*usage, 1024.0f);
        *out_loss  = (float)(*loss_acc / 8388608.0);
    }
}

// ---------------------------------------------------------------------------
extern "C" void kernel_launch(void* const* d_in, const int* in_sizes, int n_in,
                              void* d_out, int out_size, void* d_ws, size_t ws_size,
                              hipStream_t stream)
{
    const float* x_in   = (const float*)d_in[0];
    const float* emb    = (const float*)d_in[1];
    const float* ema_cs = (const float*)d_in[2];
    const float* ema_w  = (const float*)d_in[3];

    float* out_qf    = (float*)d_out;                    // [NV*64]
    float* out_enc   = out_qf + (size_t)NV * ND;         // [NV*1024]
    float* out_usage = out_enc + (size_t)NV * NK;        // [1]
    float* out_loss  = out_usage + 1;                    // [1]
    float* out_upde  = out_loss + 1;                     // [1024*64]
    float* out_uc    = out_upde + (size_t)NK * ND;       // [1024]
    float* out_updw  = out_uc + NK;                      // [1024*64]

    char* ws = (char*)d_ws;
    float*  ws_csq   = (float*)(ws);
    float*  ws_ucraw = (float*)(ws + 4096);
    float*  ws_nacc  = (float*)(ws + 8192);
    float*  ws_usage = (float*)(ws + 8196);
    double* ws_loss  = (double*)(ws + 8200);
    int*    ws_idx   = (int*)(ws + 8224);

    vq_prep<<<4, 256, 0, stream>>>(emb, ws_csq, ws_nacc, ws_usage, ws_loss);
    vq_assign<<<256, 512, 0, stream>>>(x_in, emb, ws_csq, out_qf, out_enc, ws_idx, ws_loss);
    vq_segsum<<<NK, 256, 0, stream>>>(x_in, ws_idx, ema_w, ema_cs, out_updw, ws_ucraw, ws_nacc, ws_usage);
    vq_final<<<256, 256, 0, stream>>>(ws_ucraw, ws_nacc, ws_usage, ws_loss, out_updw, out_upde, out_uc, out_usage, out_loss);
}